// Round 6
// baseline (526.448 us; speedup 1.0000x reference)
//
#include <hip/hip_runtime.h>

#define NE 500000      // edges
#define ND 50000       // nodes
#define DIMK 256       // embedding dim
#define H1 128
#define H2 64
#define EPSBN 1e-5f
#define GRID1 512
#define NT1 1954                 // layer1/2 tiles of 256 edges
#define GRID2 512

typedef _Float16 half8 __attribute__((ext_vector_type(8)));
typedef float f32x4 __attribute__((ext_vector_type(4)));
typedef unsigned short ushort8 __attribute__((ext_vector_type(8)));

static __device__ __forceinline__ half8 habs8(half8 x) {
  ushort8 u = __builtin_bit_cast(ushort8, x);
  u &= (unsigned short)0x7FFF;
  return __builtin_bit_cast(half8, u);
}
static __device__ __forceinline__ float h2f(unsigned int u) {
  return (float)__builtin_bit_cast(_Float16, (unsigned short)(u & 0xffff));
}

// ---------- counting sort of edges by src ----------
__global__ void k_zero(int* __restrict__ hist) {
  const int i = blockIdx.x * 1024 + threadIdx.x;
  if (i < ND) hist[i] = 0;
}

__global__ void k_hist(const void* __restrict__ eidx, int* __restrict__ hist) {
  const int e = blockIdx.x * 1024 + threadIdx.x;
  if (e >= NE) return;
  const unsigned* ew = (const unsigned*)eidx;
  const bool is64 = ((ew[1] | ew[3] | ew[5] | ew[7]) == 0u);
  const int s = is64 ? (int)((const long long*)eidx)[e] : ((const int*)eidx)[e];
  atomicAdd(&hist[s], 1);
}

__global__ void k_scan(const int* __restrict__ hist, int* __restrict__ offs,
                       int* __restrict__ cursor) {
  __shared__ int sc[1024];
  const int t = threadIdx.x;
  int run = 0;
  for (int c0 = 0; c0 < ND; c0 += 1024) {
    const int i = c0 + t;
    const int v = (i < ND) ? hist[i] : 0;
    sc[t] = v;
    __syncthreads();
    for (int off = 1; off < 1024; off <<= 1) {
      int x = (t >= off) ? sc[t - off] : 0;
      __syncthreads();
      sc[t] += x;
      __syncthreads();
    }
    const int incl = sc[t];
    const int total = sc[1023];
    if (i < ND) { offs[i] = run + incl - v; cursor[i] = run + incl - v; }
    run += total;
    __syncthreads();
  }
}

__global__ void k_scatter(const void* __restrict__ eidx, const float* __restrict__ grad,
                          int* __restrict__ cursor, int* __restrict__ srcs,
                          int* __restrict__ dsts, float* __restrict__ grads,
                          int* __restrict__ oeid) {
  const int e = blockIdx.x * 1024 + threadIdx.x;
  if (e >= NE) return;
  const unsigned* ew = (const unsigned*)eidx;
  const bool is64 = ((ew[1] | ew[3] | ew[5] | ew[7]) == 0u);
  int s, d;
  if (is64) { s = (int)((const long long*)eidx)[e]; d = (int)((const long long*)eidx)[NE + e]; }
  else      { s = ((const int*)eidx)[e];            d = ((const int*)eidx)[NE + e]; }
  const int p = atomicAdd(&cursor[s], 1);
  srcs[p] = s; dsts[p] = d; grads[p] = grad[e]; oeid[p] = e;
}

// ---------- prep ----------
// c0[j] = b1[j] + step @ W1[768:800, j]
__global__ void k_prep(const float* __restrict__ W1, const float* __restrict__ b1,
                       const float* __restrict__ step, float* __restrict__ c0) {
  const int j = threadIdx.x;
  if (j < H1) {
    float a = b1[j];
#pragma unroll
    for (int tt = 0; tt < 32; ++tt) a += step[tt] * W1[(768 + tt) * H1 + j];
    c0[j] = a;
  }
}

// fp32 emb -> fp16 copy
__global__ void k_prep16(const float* __restrict__ emb, _Float16* __restrict__ embh) {
  const int i = (blockIdx.x * 256 + threadIdx.x) * 8;
  const float4 a = *(const float4*)(emb + i);
  const float4 b = *(const float4*)(emb + i + 4);
  half8 h;
  h[0] = (_Float16)a.x; h[1] = (_Float16)a.y; h[2] = (_Float16)a.z; h[3] = (_Float16)a.w;
  h[4] = (_Float16)b.x; h[5] = (_Float16)b.y; h[6] = (_Float16)b.z; h[7] = (_Float16)b.w;
  *(half8*)(embh + i) = h;
}

// Fragment-ordered B for layer1
__global__ void k_prepB(const float* __restrict__ W1, _Float16* __restrict__ bfrag) {
  const int g = blockIdx.x * 256 + threadIdx.x;
  const int lane = g & 63, f = g >> 6;
  const int c = f & 7, kc = (f >> 3) & 7, s = f >> 6;
  const int row0 = s * 256 + kc * 32 + (lane >> 4) * 8;
  const int col = c * 16 + (lane & 15);
  half8 h;
#pragma unroll
  for (int j = 0; j < 8; ++j) h[j] = (_Float16)W1[(row0 + j) * H1 + col];
  *(half8*)(bfrag + (size_t)g * 8) = h;
}

// ---------- layer 1 (r4 structure, sorted edges) ----------
__global__ __launch_bounds__(256, 2)
void k_layer1(const _Float16* __restrict__ embh, const int* __restrict__ srcs,
              const int* __restrict__ dsts, const float* __restrict__ grads,
              const float* __restrict__ W1, const float* __restrict__ c0,
              const _Float16* __restrict__ bfrag, _Float16* __restrict__ x1,
              float* __restrict__ p1) {
  __shared__ int s_src[256], s_dst[256];
  __shared__ float s_g[256];
  __shared__ float s_wg[128], s_c0[128], s_sum[128], s_sq[128];

  const int t = threadIdx.x, bid = blockIdx.x;
  const int w = t >> 6, lane = t & 63, quad = lane >> 4, m15 = lane & 15;

  if (t < 128) {
    s_wg[t] = W1[800 * H1 + t];
    s_c0[t] = c0[t];
    s_sum[t] = 0.f; s_sq[t] = 0.f;
  }

  float st_s[8] = {0, 0, 0, 0, 0, 0, 0, 0}, st_q[8] = {0, 0, 0, 0, 0, 0, 0, 0};
  const half8* bp = (const half8*)bfrag;

  for (int tile = bid; tile < NT1; tile += GRID1) {
    const int base = tile * 256;
    __syncthreads();
    {
      int e = base + t; if (e >= NE) e = NE - 1;
      s_src[t] = srcs[e];
      s_dst[t] = dsts[e];
      s_g[t] = grads[e];
    }
    __syncthreads();

    const int r0 = w * 64 + m15;
    const _Float16* pu[4];
    const _Float16* pv[4];
#pragma unroll
    for (int r = 0; r < 4; ++r) {
      pu[r] = embh + (size_t)s_src[r0 + r * 16] * DIMK + quad * 8;
      pv[r] = embh + (size_t)s_dst[r0 + r * 16] * DIMK + quad * 8;
    }
    f32x4 acc[4][8];
#pragma unroll
    for (int r = 0; r < 4; ++r)
#pragma unroll
      for (int c = 0; c < 8; ++c) acc[r][c] = (f32x4)0.f;

#pragma unroll 1
    for (int kc = 0; kc < 8; ++kc) {
      half8 u[4], v[4], d[4];
#pragma unroll
      for (int r = 0; r < 4; ++r) {
        u[r] = *(const half8*)(pu[r] + kc * 32);
        v[r] = *(const half8*)(pv[r] + kc * 32);
      }
#pragma unroll
      for (int r = 0; r < 4; ++r) d[r] = habs8(u[r] - v[r]);

      half8 bu = bp[(kc * 8 + 0) * 64 + lane];
      half8 bv = bp[(64 + kc * 8 + 0) * 64 + lane];
      half8 bd = bp[(128 + kc * 8 + 0) * 64 + lane];
#pragma unroll
      for (int c = 0; c < 8; ++c) {
        half8 nbu, nbv, nbd;
        if (c < 7) {
          nbu = bp[(kc * 8 + c + 1) * 64 + lane];
          nbv = bp[(64 + kc * 8 + c + 1) * 64 + lane];
          nbd = bp[(128 + kc * 8 + c + 1) * 64 + lane];
        }
#pragma unroll
        for (int r = 0; r < 4; ++r)
          acc[r][c] = __builtin_amdgcn_mfma_f32_16x16x32_f16(u[r], bu, acc[r][c], 0, 0, 0);
#pragma unroll
        for (int r = 0; r < 4; ++r)
          acc[r][c] = __builtin_amdgcn_mfma_f32_16x16x32_f16(v[r], bv, acc[r][c], 0, 0, 0);
#pragma unroll
        for (int r = 0; r < 4; ++r)
          acc[r][c] = __builtin_amdgcn_mfma_f32_16x16x32_f16(d[r], bd, acc[r][c], 0, 0, 0);
        if (c < 7) { bu = nbu; bv = nbv; bd = nbd; }
      }
    }
#pragma unroll
    for (int r = 0; r < 4; ++r) {
      const int erow = w * 64 + r * 16 + quad * 4;
#pragma unroll
      for (int c = 0; c < 8; ++c) {
        const int colL = c * 16 + m15;
        const float wgv = s_wg[colL], c0v = s_c0[colL];
#pragma unroll
        for (int reg = 0; reg < 4; ++reg) {
          const int e = base + erow + reg;
          float x = acc[r][c][reg] + s_g[erow + reg] * wgv + c0v;
          x = fmaxf(x, 0.f);
          if (e >= NE) x = 0.f;
          st_s[c] += x; st_q[c] += x * x;
          if (e < NE) x1[(size_t)e * H1 + colL] = (_Float16)x;
        }
      }
    }
  }
  __syncthreads();
#pragma unroll
  for (int c = 0; c < 8; ++c) {
    float a = st_s[c]; a += __shfl_xor(a, 16); a += __shfl_xor(a, 32);
    float b = st_q[c]; b += __shfl_xor(b, 16); b += __shfl_xor(b, 32);
    if (lane < 16) { atomicAdd(&s_sum[c * 16 + m15], a); atomicAdd(&s_sq[c * 16 + m15], b); }
  }
  __syncthreads();
  if (t < 128) {
    p1[t * GRID1 + bid] = s_sum[t];
    p1[128 * GRID1 + t * GRID1 + bid] = s_sq[t];
  }
}

// Finalize BN1 stats, fold into W2/b2
__global__ void k_fin1(const float* __restrict__ p1, const float* __restrict__ g1,
                       const float* __restrict__ be1, const float* __restrict__ W2,
                       const float* __restrict__ b2, float* __restrict__ w2f,
                       float* __restrict__ b2f) {
  __shared__ float s1[128], t1[128];
  const int t = threadIdx.x;
  if (t < 128) {
    float s = 0.f, q = 0.f;
    const float4* rs = (const float4*)(p1 + t * GRID1);
    const float4* rq = (const float4*)(p1 + 128 * GRID1 + t * GRID1);
#pragma unroll 4
    for (int i = 0; i < GRID1 / 4; ++i) {
      float4 a = rs[i]; s += a.x + a.y + a.z + a.w;
      float4 b = rq[i]; q += b.x + b.y + b.z + b.w;
    }
    const float inv = 1.0f / (float)NE;
    float mean = s * inv;
    float var = q * inv - mean * mean;
    float sc = g1[t] * rsqrtf(var + EPSBN);
    s1[t] = sc; t1[t] = be1[t] - mean * sc;
  }
  __syncthreads();
  for (int i = t; i < H1 * H2; i += 256) w2f[i] = s1[i >> 6] * W2[i];
  if (t < 64) {
    float b = b2[t];
    for (int j = 0; j < 128; ++j) b += t1[j] * W2[j * 64 + t];
    b2f[t] = b;
  }
}

// ---------- layer 2: x2 written IN-PLACE into x1 rows (stride 128, cols 0..63) ----------
__global__ __launch_bounds__(256, 2)
void k_layer2(_Float16* __restrict__ x1, const float* __restrict__ w2f,
              const float* __restrict__ b2f, float* __restrict__ p2) {
  __shared__ __align__(16) _Float16 b_lds[8192];
  __shared__ float s_b[64], s_sum[64], s_sq[64];
  const int t = threadIdx.x, bid = blockIdx.x;
  const int w = t >> 6, lane = t & 63, quad = lane >> 4, m15 = lane & 15;

  for (int i = t; i < 8192; i += 256) {
    const int j = i & 7, li = (i >> 3) & 63, f = i >> 9;
    const int c = f & 3, kk = f >> 2;
    const int row = kk * 32 + (li >> 4) * 8 + j;
    const int col = c * 16 + (li & 15);
    b_lds[i] = (_Float16)w2f[row * H2 + col];
  }
  if (t < 64) { s_b[t] = b2f[t]; s_sum[t] = 0.f; s_sq[t] = 0.f; }
  __syncthreads();

  float st_s[4] = {0, 0, 0, 0}, st_q[4] = {0, 0, 0, 0};
  const half8* bp = (const half8*)b_lds;

  for (int job = bid; job < NT1; job += GRID2) {
    const int base = job * 256;
    const _Float16* pa[4];
#pragma unroll
    for (int r = 0; r < 4; ++r) {
      int e = base + w * 64 + r * 16 + m15; if (e >= NE) e = NE - 1;
      pa[r] = x1 + (size_t)e * H1 + quad * 8;
    }
    f32x4 acc[4][4];
#pragma unroll
    for (int r = 0; r < 4; ++r)
#pragma unroll
      for (int c = 0; c < 4; ++c) acc[r][c] = (f32x4)0.f;

#pragma unroll
    for (int kk = 0; kk < 4; ++kk) {
      half8 a[4];
#pragma unroll
      for (int r = 0; r < 4; ++r) a[r] = *(const half8*)(pa[r] + kk * 32);
#pragma unroll
      for (int c = 0; c < 4; ++c) {
        const half8 bf = bp[(kk * 4 + c) * 64 + lane];
#pragma unroll
        for (int r = 0; r < 4; ++r)
          acc[r][c] = __builtin_amdgcn_mfma_f32_16x16x32_f16(a[r], bf, acc[r][c], 0, 0, 0);
      }
    }
#pragma unroll
    for (int r = 0; r < 4; ++r) {
      const int erow = w * 64 + r * 16 + quad * 4;
#pragma unroll
      for (int c = 0; c < 4; ++c) {
        const int colL = c * 16 + m15;
        const float bv = s_b[colL];
#pragma unroll
        for (int reg = 0; reg < 4; ++reg) {
          const int e = base + erow + reg;
          float x = acc[r][c][reg] + bv;
          x = fmaxf(x, 0.f);
          if (e >= NE) x = 0.f;
          st_s[c] += x; st_q[c] += x * x;
          // in-place: x2 row e occupies x1 row e's first 64 halves
          if (e < NE) x1[(size_t)e * H1 + colL] = (_Float16)x;
        }
      }
    }
  }
  __syncthreads();
#pragma unroll
  for (int c = 0; c < 4; ++c) {
    float a = st_s[c]; a += __shfl_xor(a, 16); a += __shfl_xor(a, 32);
    float b = st_q[c]; b += __shfl_xor(b, 16); b += __shfl_xor(b, 32);
    if (lane < 16) { atomicAdd(&s_sum[c * 16 + m15], a); atomicAdd(&s_sq[c * 16 + m15], b); }
  }
  __syncthreads();
  if (t < 64) {
    p2[t * GRID2 + bid] = s_sum[t];
    p2[64 * GRID2 + t * GRID2 + bid] = s_sq[t];
  }
}

// Finalize BN2, fold into W3/b3
__global__ void k_fin2(const float* __restrict__ p2, const float* __restrict__ g2,
                       const float* __restrict__ be2, const float* __restrict__ W3,
                       const float* __restrict__ b3, float* __restrict__ w3f,
                       float* __restrict__ b3f) {
  __shared__ float tp[64];
  const int t = threadIdx.x;
  if (t < 64) {
    float s = 0.f, q = 0.f;
    const float4* rs = (const float4*)(p2 + t * GRID2);
    const float4* rq = (const float4*)(p2 + 64 * GRID2 + t * GRID2);
#pragma unroll 4
    for (int i = 0; i < GRID2 / 4; ++i) {
      float4 a = rs[i]; s += a.x + a.y + a.z + a.w;
      float4 b = rq[i]; q += b.x + b.y + b.z + b.w;
    }
    const float inv = 1.0f / (float)NE;
    float mean = s * inv;
    float var = q * inv - mean * mean;
    float sc = g2[t] * rsqrtf(var + EPSBN);
    float tt = be2[t] - mean * sc;
    w3f[t] = sc * W3[t];
    tp[t] = tt * W3[t];
  }
  __syncthreads();
  if (t == 0) {
    float b = b3[0];
    for (int j = 0; j < 64; ++j) b += tp[j];
    b3f[0] = b;
  }
}

// out[oeid[e]] = tanh(x2[e] @ w3f + b3f); x2 in-place in x1 (stride 128)
__global__ __launch_bounds__(256)
void k_out(const unsigned short* __restrict__ x2, const int* __restrict__ oeid,
           const float* __restrict__ w3f, const float* __restrict__ b3f,
           float* __restrict__ out) {
  __shared__ float s_w[64];
  __shared__ float s_b;
  const int t = threadIdx.x;
  if (t < 64) s_w[t] = w3f[t];
  if (t == 0) s_b = b3f[0];
  __syncthreads();
  const int gid = blockIdx.x * 256 + t;
  const int e = gid >> 2, p = gid & 3;
  if (e < NE) {
    const uint4* r = (const uint4*)(x2 + (size_t)e * H1 + p * 16);
    float s = 0.f;
#pragma unroll
    for (int i = 0; i < 2; ++i) {
      const uint4 u = r[i];
      const int jb = p * 16 + i * 8;
      s += h2f(u.x) * s_w[jb + 0] + h2f(u.x >> 16) * s_w[jb + 1];
      s += h2f(u.y) * s_w[jb + 2] + h2f(u.y >> 16) * s_w[jb + 3];
      s += h2f(u.z) * s_w[jb + 4] + h2f(u.z >> 16) * s_w[jb + 5];
      s += h2f(u.w) * s_w[jb + 6] + h2f(u.w >> 16) * s_w[jb + 7];
    }
    s += __shfl_xor(s, 1);
    s += __shfl_xor(s, 2);
    if (p == 0) out[oeid[e]] = tanhf(s + s_b);
  }
}

extern "C" void kernel_launch(void* const* d_in, const int* in_sizes, int n_in,
                              void* d_out, int out_size, void* d_ws, size_t ws_size,
                              hipStream_t stream) {
  const float* emb  = (const float*)d_in[0];
  const float* grad = (const float*)d_in[1];
  const float* step = (const float*)d_in[2];
  const float* W1   = (const float*)d_in[3];
  const float* b1   = (const float*)d_in[4];
  const float* g1   = (const float*)d_in[5];
  const float* be1  = (const float*)d_in[6];
  const float* W2   = (const float*)d_in[7];
  const float* b2   = (const float*)d_in[8];
  const float* g2   = (const float*)d_in[9];
  const float* be2  = (const float*)d_in[10];
  const float* W3   = (const float*)d_in[11];
  const float* b3   = (const float*)d_in[12];
  const void*  eidx = (const void*)d_in[13];
  float* out = (float*)d_out;

  char* ws = (char*)d_ws;
  _Float16* embh  = (_Float16*)(ws + 0);           // 25,600,000
  _Float16* bfrag = (_Float16*)(ws + 25600000LL);  // 196,608
  float*    c0    = (float*)(ws + 25796608LL);     // 512
  int*   hist   = (int*)(ws + 25800000LL);         // 200,000
  int*   offs   = (int*)(ws + 26000000LL);         // 200,000
  int*   cursor = (int*)(ws + 26200000LL);         // 200,000
  int*   srcs   = (int*)(ws + 26400000LL);         // 2,000,000
  int*   dsts   = (int*)(ws + 28400000LL);         // 2,000,000
  float* grads  = (float*)(ws + 30400000LL);       // 2,000,000
  int*   oeid   = (int*)(ws + 32400000LL);         // 2,000,000  (survives to k_out)
  _Float16* x1  = (_Float16*)(ws + 64000000LL);    // 128,000,000 (x2 in-place)
  float* p1  = (float*)(ws + 192000000LL);         // 524,288
  float* p2  = (float*)(ws + 192524288LL);         // 262,144
  float* w2f = (float*)(ws + 192786432LL);         // 32,768
  float* b2f = (float*)(ws + 192819200LL);         // 256
  float* w3f = (float*)(ws + 192819456LL);         // 256
  float* b3f = (float*)(ws + 192819712LL);         // 16

  k_zero   <<<49,  1024, 0, stream>>>(hist);
  k_hist   <<<489, 1024, 0, stream>>>(eidx, hist);
  k_scan   <<<1,   1024, 0, stream>>>(hist, offs, cursor);
  k_scatter<<<489, 1024, 0, stream>>>(eidx, grad, cursor, srcs, dsts, grads, oeid);
  k_prep   <<<1,    256, 0, stream>>>(W1, b1, step, c0);
  k_prep16 <<<6250, 256, 0, stream>>>(emb, embh);
  k_prepB  <<<48,   256, 0, stream>>>(W1, bfrag);
  k_layer1 <<<GRID1,256, 0, stream>>>(embh, srcs, dsts, grads, W1, c0, bfrag, x1, p1);
  k_fin1   <<<1,    256, 0, stream>>>(p1, g1, be1, W2, b2, w2f, b2f);
  k_layer2 <<<GRID2,256, 0, stream>>>(x1, w2f, b2f, p2);
  k_fin2   <<<1,    128, 0, stream>>>(p2, g2, be2, W3, b3, w3f, b3f);
  k_out    <<<7813, 256, 0, stream>>>((const unsigned short*)x1, oeid, w3f, b3f, out);
}